// Round 4
// baseline (310.554 us; speedup 1.0000x reference)
//
#include <hip/hip_runtime.h>
#include <math.h>

typedef __attribute__((ext_vector_type(8))) short short8;
typedef __attribute__((ext_vector_type(4))) float f32x4;

__device__ __forceinline__ float b2f(short s){
  return __uint_as_float(((unsigned int)(unsigned short)s) << 16);
}
__device__ __forceinline__ short f2b(float f){
  unsigned int u = __float_as_uint(f);
  u = (u + 0x7fffu + ((u >> 16) & 1u)) >> 16;
  return (short)u;
}
__device__ __forceinline__ unsigned pk2(float lo, float hi){
  return ((unsigned)(unsigned short)f2b(hi) << 16) | (unsigned)(unsigned short)f2b(lo);
}

// ---------------- weight f32 -> bf16 conversion ----------------
__global__ __launch_bounds__(256) void cvt_w(
    const float* __restrict__ s0, const float* __restrict__ s1,
    const float* __restrict__ s2, const float* __restrict__ s3,
    const float* __restrict__ s4, const float* __restrict__ s5,
    short* __restrict__ dst)
{
  const float* srcs[6] = {s0, s1, s2, s3, s4, s5};
  int i = blockIdx.x * 256 + threadIdx.x;       // 6*65536 total
  dst[i] = f2b(srcs[i >> 16][i & 65535]);
}

// ---------------- LayerNorm: f32 in, bf16 out ----------------
__global__ __launch_bounds__(256) void ln_k(
    const float* __restrict__ x, const float* __restrict__ g,
    const float* __restrict__ bta, short* __restrict__ y)
{
  const int row = blockIdx.x, t = threadIdx.x;
  const size_t base = (size_t)row * 256;
  float v = x[base + t];
  float s1 = v, s2 = v * v;
  #pragma unroll
  for (int off = 32; off; off >>= 1){ s1 += __shfl_down(s1, off); s2 += __shfl_down(s2, off); }
  __shared__ float a1[4], a2[4];
  __shared__ float mu_s, rs_s;
  if ((t & 63) == 0){ a1[t >> 6] = s1; a2[t >> 6] = s2; }
  __syncthreads();
  if (t == 0){
    float S1 = a1[0] + a1[1] + a1[2] + a1[3];
    float S2 = a2[0] + a2[1] + a2[2] + a2[3];
    float mu = S1 * 0.00390625f;
    float var = S2 * 0.00390625f - mu * mu;
    mu_s = mu; rs_s = rsqrtf(var + 1e-5f);
  }
  __syncthreads();
  y[base + t] = f2b((v - mu_s) * rs_s * g[t] + bta[t]);
}

// ---------------- wide GEMM: C[M,256] = A[M,256] @ W[256,256]^T + b ----------------
// Block = 64 rows x FULL 256 cols, 4 waves (wave: 16 rows x 256 cols, acc[16] f32x4).
// Epilogue: GELU / f32 residual / f32 out / bf16 out / Vt-permuted out / fused row-LN.
template<int RES, int GELU, int OF, int OB, int OT, int LN>
__global__ __launch_bounds__(256, 4) void gemmW(
    const short* __restrict__ A, const short* __restrict__ W,
    const float* __restrict__ bias, const float* __restrict__ res,
    float* __restrict__ outF, short* __restrict__ outB,
    const float* __restrict__ lng, const float* __restrict__ lnb,
    short* __restrict__ outL)
{
  __shared__ short As[64][40];
  __shared__ short Ws[256][40];
  const int tid = threadIdx.x;
  const int m0 = blockIdx.x << 6;
  const int w = tid >> 6, lane = tid & 63;
  const int l15 = lane & 15, g = lane >> 4;
  f32x4 acc[16];
  #pragma unroll
  for (int nt = 0; nt < 16; ++nt) acc[nt] = {0.f, 0.f, 0.f, 0.f};

  for (int k0 = 0; k0 < 256; k0 += 32){
    if (k0) __syncthreads();
    {
      int row = tid >> 2, c0 = (tid & 3) << 3;
      *(short8*)&As[row][c0] = *(const short8*)&A[(size_t)(m0 + row) * 256 + k0 + c0];
      #pragma unroll
      for (int it = 0; it < 4; ++it){
        int rw = (it << 6) + (tid >> 2);
        *(short8*)&Ws[rw][c0] = *(const short8*)&W[(size_t)rw * 256 + k0 + c0];
      }
    }
    __syncthreads();
    short8 af = *(const short8*)&As[(w << 4) + l15][g << 3];
    #pragma unroll
    for (int nt = 0; nt < 16; ++nt){
      short8 bf = *(const short8*)&Ws[(nt << 4) + l15][g << 3];
      acc[nt] = __builtin_amdgcn_mfma_f32_16x16x32_bf16(af, bf, acc[nt], 0, 0, 0);
    }
  }

  const int row_l = (w << 4) + (g << 2);     // + r = wave's row within block
  #pragma unroll
  for (int nt = 0; nt < 16; ++nt){
    const int col = (nt << 4) + l15;
    const float bv = bias[col];
    #pragma unroll
    for (int r = 0; r < 4; ++r){
      const size_t idx = (size_t)(m0 + row_l + r) * 256 + col;
      float v = acc[nt][r] + bv;
      if (GELU) v = 0.5f * v * (1.0f + erff(v * 0.70710678118f));
      if (RES) v += res[idx];
      if (OF) outF[idx] = v;
      acc[nt][r] = v;
      if (OB){
        if (OT){
          const int m = m0 + row_l + r;
          const int j = m & 255;
          const int jp = (j & ~31) | (((j >> 2) & 3) << 3) | (((j >> 4) & 1) << 2) | (j & 3);
          outB[(size_t)((m & ~255) | col) * 256 + jp] = f2b(v);
        } else {
          outB[idx] = f2b(v);
        }
      }
    }
  }
  if (LN){
    #pragma unroll
    for (int r = 0; r < 4; ++r){
      float s1 = 0.f, s2 = 0.f;
      #pragma unroll
      for (int nt = 0; nt < 16; ++nt){ float v = acc[nt][r]; s1 += v; s2 += v * v; }
      #pragma unroll
      for (int off = 1; off < 16; off <<= 1){ s1 += __shfl_xor(s1, off); s2 += __shfl_xor(s2, off); }
      const float mu = s1 * 0.00390625f;
      const float rs = rsqrtf(s2 * 0.00390625f - mu * mu + 1e-5f);
      #pragma unroll
      for (int nt = 0; nt < 16; ++nt){
        const int col = (nt << 4) + l15;
        outL[(size_t)(m0 + row_l + r) * 256 + col] =
            f2b((acc[nt][r] - mu) * rs * lng[col] + lnb[col]);
      }
    }
  }
}

// ---------------- fused MFMA attention (P in registers, 8 waves) ----------------
// Block: 128 q-rows, 8 waves (16 rows each), all 4 heads.
// Swapped QK^T: acc = mfma(K_frag, Q_frag) -> lane(l15,g) holds
// P[q = l15][kv = 16*nt + 4*g + r]  (full kv row lane-local across nt,r).
// Softmax fully in-register; PV uses kv-permuted Vt so A-frags are in-lane packs.
__global__ __launch_bounds__(512, 4) void attn_k(
    const short* __restrict__ Qb, const short* __restrict__ Kb,
    const short* __restrict__ Vtg, const float* __restrict__ cw,
    short* __restrict__ ctx, float* __restrict__ am_out)
{
  __shared__ short Kp[256][80];   // stride 160B
  __shared__ short Vt[64][272];   // stride 544B
  const int b = blockIdx.y;
  const int q0 = blockIdx.x << 7;
  const int tid = threadIdx.x;
  const int w = tid >> 6, lane = tid & 63;
  const int l15 = lane & 15, g = lane >> 4;
  const size_t qw = (size_t)b * 4096 + q0 + (w << 4);   // wave's first q row

  // clustering weights (bf16-packed) + attn_matrix accumulator, in registers.
  unsigned cwp[16][2];
  f32x4 am[16];
  #pragma unroll
  for (int nt = 0; nt < 16; ++nt){
    f32x4 c = *(const f32x4*)&cw[(qw + l15) * 256 + (nt << 4) + (g << 2)];
    cwp[nt][0] = pk2(c[0], c[1]);
    cwp[nt][1] = pk2(c[2], c[3]);
    am[nt] = {0.f, 0.f, 0.f, 0.f};
  }

  for (int h = 0; h < 4; ++h){
    __syncthreads();                       // Kp/Vt free from prior head
    #pragma unroll
    for (int it = 0; it < 4; ++it){        // stage K_h (2048 x 16B chunks / 512 thr)
      int idx = tid + (it << 9);
      int row = idx >> 3, c0 = (idx & 7) << 3;
      *(short8*)&Kp[row][c0] = *(const short8*)&Kb[((size_t)(b * 256 + row) << 8) + (h << 6) + c0];
    }
    #pragma unroll
    for (int it = 0; it < 4; ++it){        // stage Vt_h (cols pre-permuted in global)
      int idx = tid + (it << 9);
      int row = idx >> 5, c0 = (idx & 31) << 3;
      *(short8*)&Vt[row][c0] = *(const short8*)&Vtg[((size_t)(b * 256 + (h << 6) + row) << 8) + c0];
    }
    short8 qf0 = *(const short8*)&Qb[(qw + l15) * 256 + (h << 6) + (g << 3)];
    short8 qf1 = *(const short8*)&Qb[(qw + l15) * 256 + (h << 6) + 32 + (g << 3)];
    __syncthreads();

    // ---- scores: swapped operands ----
    f32x4 acc[16];
    #pragma unroll
    for (int nt = 0; nt < 16; ++nt) acc[nt] = {0.f, 0.f, 0.f, 0.f};
    #pragma unroll
    for (int nt = 0; nt < 16; ++nt){
      short8 kf0 = *(const short8*)&Kp[(nt << 4) + l15][(g << 3)];
      acc[nt] = __builtin_amdgcn_mfma_f32_16x16x32_bf16(kf0, qf0, acc[nt], 0, 0, 0);
      short8 kf1 = *(const short8*)&Kp[(nt << 4) + l15][32 + (g << 3)];
      acc[nt] = __builtin_amdgcn_mfma_f32_16x16x32_bf16(kf1, qf1, acc[nt], 0, 0, 0);
    }
    // ---- softmax, fully in-lane (row q = l15; partners at lane^16, lane^32) ----
    float mx = -3.4e38f;
    #pragma unroll
    for (int nt = 0; nt < 16; ++nt){
      float c0 = __uint_as_float(cwp[nt][0] << 16);
      float c1 = __uint_as_float(cwp[nt][0] & 0xffff0000u);
      float c2 = __uint_as_float(cwp[nt][1] << 16);
      float c3 = __uint_as_float(cwp[nt][1] & 0xffff0000u);
      acc[nt][0] = acc[nt][0] * 0.125f + c0;
      acc[nt][1] = acc[nt][1] * 0.125f + c1;
      acc[nt][2] = acc[nt][2] * 0.125f + c2;
      acc[nt][3] = acc[nt][3] * 0.125f + c3;
      mx = fmaxf(mx, fmaxf(fmaxf(acc[nt][0], acc[nt][1]), fmaxf(acc[nt][2], acc[nt][3])));
    }
    mx = fmaxf(mx, __shfl_xor(mx, 16));
    mx = fmaxf(mx, __shfl_xor(mx, 32));
    float sm = 0.f;
    #pragma unroll
    for (int nt = 0; nt < 16; ++nt){
      #pragma unroll
      for (int r = 0; r < 4; ++r){
        float e = __expf(acc[nt][r] - mx);
        acc[nt][r] = e; sm += e;
      }
    }
    sm += __shfl_xor(sm, 16);
    sm += __shfl_xor(sm, 32);
    float inv = 1.f / sm;
    #pragma unroll
    for (int nt = 0; nt < 16; ++nt){
      #pragma unroll
      for (int r = 0; r < 4; ++r){
        float p = acc[nt][r] * inv;
        acc[nt][r] = p;
        am[nt][r] += 0.25f * p;
      }
    }
    // ---- ctx = P @ V : A-frags are in-lane packs (kv-permuted Vt cols match) ----
    f32x4 oc[4] = {{0,0,0,0},{0,0,0,0},{0,0,0,0},{0,0,0,0}};
    #pragma unroll
    for (int kk = 0; kk < 8; ++kk){
      union { short8 s; unsigned u[4]; } pa;
      pa.u[0] = pk2(acc[2 * kk][0],     acc[2 * kk][1]);
      pa.u[1] = pk2(acc[2 * kk][2],     acc[2 * kk][3]);
      pa.u[2] = pk2(acc[2 * kk + 1][0], acc[2 * kk + 1][1]);
      pa.u[3] = pk2(acc[2 * kk + 1][2], acc[2 * kk + 1][3]);
      #pragma unroll
      for (int n2 = 0; n2 < 4; ++n2){
        short8 vb = *(const short8*)&Vt[(n2 << 4) + l15][(kk << 5) + (g << 3)];
        oc[n2] = __builtin_amdgcn_mfma_f32_16x16x32_bf16(pa.s, vb, oc[n2], 0, 0, 0);
      }
    }
    // lane holds ctx[q = 4g + r][d = 16*n2 + l15]
    #pragma unroll
    for (int n2 = 0; n2 < 4; ++n2)
      #pragma unroll
      for (int r = 0; r < 4; ++r)
        ctx[((size_t)b * 4096 + q0 + (w << 4) + (g << 2) + r) * 256 + (h << 6) + (n2 << 4) + l15]
            = f2b(oc[n2][r]);
  }
  #pragma unroll
  for (int nt = 0; nt < 16; ++nt)
    *(f32x4*)&am_out[(qw + l15) * 256 + (nt << 4) + (g << 2)] = am[nt];
}

extern "C" void kernel_launch(void* const* d_in, const int* in_sizes, int n_in,
                              void* d_out, int out_size, void* d_ws, size_t ws_size,
                              hipStream_t stream)
{
  const float* node_emb = (const float*)d_in[0];
  const float* cluster  = (const float*)d_in[1];
  const float* cw       = (const float*)d_in[2];
  const float* ln_q_g   = (const float*)d_in[3];
  const float* ln_q_b   = (const float*)d_in[4];
  const float* ln_kv_g  = (const float*)d_in[5];
  const float* ln_kv_b  = (const float*)d_in[6];
  const float* ln_o_g   = (const float*)d_in[7];
  const float* ln_o_b   = (const float*)d_in[8];
  const float* W_q  = (const float*)d_in[9];  const float* b_q  = (const float*)d_in[10];
  const float* W_k  = (const float*)d_in[11]; const float* b_k  = (const float*)d_in[12];
  const float* W_v  = (const float*)d_in[13]; const float* b_v  = (const float*)d_in[14];
  const float* W_o  = (const float*)d_in[15]; const float* b_o  = (const float*)d_in[16];
  const float* W_m1 = (const float*)d_in[17]; const float* b_m1 = (const float*)d_in[18];
  const float* W_m2 = (const float*)d_in[19]; const float* b_m2 = (const float*)d_in[20];

  char* ws = (char*)d_ws;
  short* Wbf  = (short*)ws;                                   // 786,432 B (6 x 64K bf16)
  short* n1   = (short*)(ws + 786432);                        // 16.78 MB: q_in -> ctx -> h1
  short* n2   = (short*)(ws + 786432 + 16777216);             // 16.78 MB: Q -> h_ln
  short* kvin = (short*)(ws + 786432 + 2 * 16777216);         // 1 MB
  short* Kb   = (short*)(ws + 786432 + 2 * 16777216 + 1048576);
  short* vt   = (short*)(ws + 786432 + 2 * 16777216 + 2 * 1048576);  // V^T, kv-permuted cols

  float* xbuf = (float*)d_out;            // first half: x, later overwritten by final out
  float* amof = (float*)d_out + 8388608;  // second half: attn_matrix

  cvt_w<<<1536, 256, 0, stream>>>(W_q, W_k, W_v, W_o, W_m1, W_m2, Wbf);
  ln_k<<<32768, 256, 0, stream>>>(node_emb, ln_q_g, ln_q_b, n1);
  ln_k<<<2048, 256, 0, stream>>>(cluster, ln_kv_g, ln_kv_b, kvin);
  // Q / K / V projections (V written transposed + kv-permuted into vt)
  gemmW<0,0,0,1,0,0><<<512, 256, 0, stream>>>(n1,   Wbf,          b_q, nullptr, nullptr, n2, nullptr, nullptr, nullptr);
  gemmW<0,0,0,1,0,0><<<32,  256, 0, stream>>>(kvin, Wbf + 65536,  b_k, nullptr, nullptr, Kb, nullptr, nullptr, nullptr);
  gemmW<0,0,0,1,1,0><<<32,  256, 0, stream>>>(kvin, Wbf + 131072, b_v, nullptr, nullptr, vt, nullptr, nullptr, nullptr);
  // attention (ctx -> n1, attn_matrix -> d_out 2nd half)
  attn_k<<<dim3(32, 8), 512, 0, stream>>>(n2, Kb, vt, cw, n1, amof);
  // O proj + residual -> x (f32) AND fused LN(x) -> n2 (bf16)
  gemmW<1,0,1,0,0,1><<<512, 256, 0, stream>>>(n1, Wbf + 196608, b_o, node_emb, xbuf, nullptr, ln_o_g, ln_o_b, n2);
  // MLP1 + GELU -> n1 ; MLP2 + residual(x) -> final out (in-place over x)
  gemmW<0,1,0,1,0,0><<<512, 256, 0, stream>>>(n2, Wbf + 262144, b_m1, nullptr, nullptr, n1, nullptr, nullptr, nullptr);
  gemmW<1,0,1,0,0,0><<<512, 256, 0, stream>>>(n1, Wbf + 327680, b_m2, xbuf, xbuf, nullptr, nullptr, nullptr, nullptr);
}

// Round 5
// 238.891 us; speedup vs baseline: 1.3000x; 1.3000x over previous
//
#include <hip/hip_runtime.h>
#include <math.h>

typedef __attribute__((ext_vector_type(8))) short short8;
typedef __attribute__((ext_vector_type(4))) float f32x4;

__device__ __forceinline__ float b2f(short s){
  return __uint_as_float(((unsigned int)(unsigned short)s) << 16);
}
__device__ __forceinline__ short f2b(float f){
  unsigned int u = __float_as_uint(f);
  u = (u + 0x7fffu + ((u >> 16) & 1u)) >> 16;
  return (short)u;
}
__device__ __forceinline__ unsigned pk2(float lo, float hi){
  return ((unsigned)(unsigned short)f2b(hi) << 16) | (unsigned)(unsigned short)f2b(lo);
}

// ---------------- weight f32 -> bf16 conversion ----------------
__global__ __launch_bounds__(256) void cvt_w(
    const float* __restrict__ s0, const float* __restrict__ s1,
    const float* __restrict__ s2, const float* __restrict__ s3,
    const float* __restrict__ s4, const float* __restrict__ s5,
    short* __restrict__ dst)
{
  const float* srcs[6] = {s0, s1, s2, s3, s4, s5};
  int i = blockIdx.x * 256 + threadIdx.x;       // 6*65536 total
  dst[i] = f2b(srcs[i >> 16][i & 65535]);
}

// ---------------- LayerNorm: f32 in, bf16 out ----------------
__global__ __launch_bounds__(256) void ln_k(
    const float* __restrict__ x, const float* __restrict__ g,
    const float* __restrict__ bta, short* __restrict__ y)
{
  const int row = blockIdx.x, t = threadIdx.x;
  const size_t base = (size_t)row * 256;
  float v = x[base + t];
  float s1 = v, s2 = v * v;
  #pragma unroll
  for (int off = 32; off; off >>= 1){ s1 += __shfl_down(s1, off); s2 += __shfl_down(s2, off); }
  __shared__ float a1[4], a2[4];
  __shared__ float mu_s, rs_s;
  if ((t & 63) == 0){ a1[t >> 6] = s1; a2[t >> 6] = s2; }
  __syncthreads();
  if (t == 0){
    float S1 = a1[0] + a1[1] + a1[2] + a1[3];
    float S2 = a2[0] + a2[1] + a2[2] + a2[3];
    float mu = S1 * 0.00390625f;
    float var = S2 * 0.00390625f - mu * mu;
    mu_s = mu; rs_s = rsqrtf(var + 1e-5f);
  }
  __syncthreads();
  y[base + t] = f2b((v - mu_s) * rs_s * g[t] + bta[t]);
}

// ---------------- wide GEMM: C[M,256] = A[M,256] @ W[256,256]^T + b ----------------
// Block = 64 rows x FULL 256 cols, 4 waves (wave: 16 rows x 256 cols, acc[16] f32x4).
// __launch_bounds__(256,2): VGPR cap 256 -> NO spill (r4's (256,4) cap 128 spilled).
template<int RES, int GELU, int OF, int OB, int OT, int LN>
__global__ __launch_bounds__(256, 2) void gemmW(
    const short* __restrict__ A, const short* __restrict__ W,
    const float* __restrict__ bias, const float* __restrict__ res,
    float* __restrict__ outF, short* __restrict__ outB,
    const float* __restrict__ lng, const float* __restrict__ lnb,
    short* __restrict__ outL)
{
  __shared__ short As[64][40];
  __shared__ short Ws[256][40];
  const int tid = threadIdx.x;
  const int m0 = blockIdx.x << 6;
  const int w = tid >> 6, lane = tid & 63;
  const int l15 = lane & 15, g = lane >> 4;
  f32x4 acc[16];
  #pragma unroll
  for (int nt = 0; nt < 16; ++nt) acc[nt] = {0.f, 0.f, 0.f, 0.f};

  for (int k0 = 0; k0 < 256; k0 += 32){
    if (k0) __syncthreads();
    {
      int row = tid >> 2, c0 = (tid & 3) << 3;
      *(short8*)&As[row][c0] = *(const short8*)&A[(size_t)(m0 + row) * 256 + k0 + c0];
      #pragma unroll
      for (int it = 0; it < 4; ++it){
        int rw = (it << 6) + (tid >> 2);
        *(short8*)&Ws[rw][c0] = *(const short8*)&W[(size_t)rw * 256 + k0 + c0];
      }
    }
    __syncthreads();
    short8 af = *(const short8*)&As[(w << 4) + l15][g << 3];
    #pragma unroll
    for (int nt = 0; nt < 16; ++nt){
      short8 bf = *(const short8*)&Ws[(nt << 4) + l15][g << 3];
      acc[nt] = __builtin_amdgcn_mfma_f32_16x16x32_bf16(af, bf, acc[nt], 0, 0, 0);
    }
  }

  const int row_l = (w << 4) + (g << 2);     // + r = wave's row within block
  #pragma unroll
  for (int nt = 0; nt < 16; ++nt){
    const int col = (nt << 4) + l15;
    const float bv = bias[col];
    #pragma unroll
    for (int r = 0; r < 4; ++r){
      const size_t idx = (size_t)(m0 + row_l + r) * 256 + col;
      float v = acc[nt][r] + bv;
      if (GELU) v = 0.5f * v * (1.0f + erff(v * 0.70710678118f));
      if (RES) v += res[idx];
      if (OF) outF[idx] = v;
      acc[nt][r] = v;
      if (OB){
        if (OT){
          const int m = m0 + row_l + r;
          const int j = m & 255;
          const int jp = (j & ~31) | (((j >> 2) & 3) << 3) | (((j >> 4) & 1) << 2) | (j & 3);
          outB[(size_t)((m & ~255) | col) * 256 + jp] = f2b(v);
        } else {
          outB[idx] = f2b(v);
        }
      }
    }
  }
  if (LN){
    #pragma unroll
    for (int r = 0; r < 4; ++r){
      float s1 = 0.f, s2 = 0.f;
      #pragma unroll
      for (int nt = 0; nt < 16; ++nt){ float v = acc[nt][r]; s1 += v; s2 += v * v; }
      #pragma unroll
      for (int off = 1; off < 16; off <<= 1){ s1 += __shfl_xor(s1, off); s2 += __shfl_xor(s2, off); }
      const float mu = s1 * 0.00390625f;
      const float rs = rsqrtf(s2 * 0.00390625f - mu * mu + 1e-5f);
      #pragma unroll
      for (int nt = 0; nt < 16; ++nt){
        const int col = (nt << 4) + l15;
        outL[(size_t)(m0 + row_l + r) * 256 + col] =
            f2b((acc[nt][r] - mu) * rs * lng[col] + lnb[col]);
      }
    }
  }
}

// ---------------- fused MFMA attention: LDS-free, barrier-free ----------------
// Block: 64 q-rows, 4 independent waves (16 q-rows each), all 4 heads.
// K/V are L2/L3-resident (2 MB total): each wave reads its own B-fragments
// straight from global (16 rows x 64B contiguous per fragment-load group).
// Swapped QK^T: acc = mfma(K_frag, Q_frag) -> lane(l15,g) holds
// P[q = l15][kv = 16*nt + 4*g + r]; softmax fully in-lane; PV via kv-permuted Vt.
__global__ __launch_bounds__(256, 2) void attn_k(
    const short* __restrict__ Qb, const short* __restrict__ Kb,
    const short* __restrict__ Vtg, const float* __restrict__ cw,
    short* __restrict__ ctx, float* __restrict__ am_out)
{
  const int b = blockIdx.y;
  const int q0 = blockIdx.x << 6;
  const int tid = threadIdx.x;
  const int w = tid >> 6, lane = tid & 63;
  const int l15 = lane & 15, g = lane >> 4;
  const size_t qw = (size_t)b * 4096 + q0 + (w << 4);   // wave's first q row

  // clustering weights (bf16-packed) + attn_matrix accumulator, in registers.
  unsigned cwp[16][2];
  f32x4 am[16];
  #pragma unroll
  for (int nt = 0; nt < 16; ++nt){
    f32x4 c = *(const f32x4*)&cw[(qw + l15) * 256 + (nt << 4) + (g << 2)];
    cwp[nt][0] = pk2(c[0], c[1]);
    cwp[nt][1] = pk2(c[2], c[3]);
    am[nt] = {0.f, 0.f, 0.f, 0.f};
  }

  const short* Kh0 = &Kb[((size_t)b * 256) << 8];       // K rows base for this batch
  const short* Vh0 = &Vtg[((size_t)b * 256) << 8];      // Vt rows base

  for (int h = 0; h < 4; ++h){
    short8 qf0 = *(const short8*)&Qb[(qw + l15) * 256 + (h << 6) + (g << 3)];
    short8 qf1 = *(const short8*)&Qb[(qw + l15) * 256 + (h << 6) + 32 + (g << 3)];

    // ---- scores: B-frags (K rows) straight from global/L2 ----
    f32x4 acc[16];
    #pragma unroll
    for (int nt = 0; nt < 16; ++nt) acc[nt] = {0.f, 0.f, 0.f, 0.f};
    #pragma unroll
    for (int nt = 0; nt < 16; ++nt){
      short8 kf0 = *(const short8*)&Kh0[((size_t)((nt << 4) + l15) << 8) + (h << 6) + (g << 3)];
      acc[nt] = __builtin_amdgcn_mfma_f32_16x16x32_bf16(kf0, qf0, acc[nt], 0, 0, 0);
      short8 kf1 = *(const short8*)&Kh0[((size_t)((nt << 4) + l15) << 8) + (h << 6) + 32 + (g << 3)];
      acc[nt] = __builtin_amdgcn_mfma_f32_16x16x32_bf16(kf1, qf1, acc[nt], 0, 0, 0);
    }
    // ---- softmax, fully in-lane (row q = l15; partners at lane^16, lane^32) ----
    float mx = -3.4e38f;
    #pragma unroll
    for (int nt = 0; nt < 16; ++nt){
      float c0 = __uint_as_float(cwp[nt][0] << 16);
      float c1 = __uint_as_float(cwp[nt][0] & 0xffff0000u);
      float c2 = __uint_as_float(cwp[nt][1] << 16);
      float c3 = __uint_as_float(cwp[nt][1] & 0xffff0000u);
      acc[nt][0] = acc[nt][0] * 0.125f + c0;
      acc[nt][1] = acc[nt][1] * 0.125f + c1;
      acc[nt][2] = acc[nt][2] * 0.125f + c2;
      acc[nt][3] = acc[nt][3] * 0.125f + c3;
      mx = fmaxf(mx, fmaxf(fmaxf(acc[nt][0], acc[nt][1]), fmaxf(acc[nt][2], acc[nt][3])));
    }
    mx = fmaxf(mx, __shfl_xor(mx, 16));
    mx = fmaxf(mx, __shfl_xor(mx, 32));
    float sm = 0.f;
    #pragma unroll
    for (int nt = 0; nt < 16; ++nt){
      #pragma unroll
      for (int r = 0; r < 4; ++r){
        float e = __expf(acc[nt][r] - mx);
        acc[nt][r] = e; sm += e;
      }
    }
    sm += __shfl_xor(sm, 16);
    sm += __shfl_xor(sm, 32);
    float inv = 1.f / sm;
    #pragma unroll
    for (int nt = 0; nt < 16; ++nt){
      #pragma unroll
      for (int r = 0; r < 4; ++r){
        float p = acc[nt][r] * inv;
        acc[nt][r] = p;
        am[nt][r] += 0.25f * p;
      }
    }
    // ---- ctx = P @ V : A-frags in-lane packs; V-frags (Vt rows) from global/L2 ----
    f32x4 oc[4] = {{0,0,0,0},{0,0,0,0},{0,0,0,0},{0,0,0,0}};
    #pragma unroll
    for (int kk = 0; kk < 8; ++kk){
      union { short8 s; unsigned u[4]; } pa;
      pa.u[0] = pk2(acc[2 * kk][0],     acc[2 * kk][1]);
      pa.u[1] = pk2(acc[2 * kk][2],     acc[2 * kk][3]);
      pa.u[2] = pk2(acc[2 * kk + 1][0], acc[2 * kk + 1][1]);
      pa.u[3] = pk2(acc[2 * kk + 1][2], acc[2 * kk + 1][3]);
      #pragma unroll
      for (int n2 = 0; n2 < 4; ++n2){
        short8 vb = *(const short8*)&Vh0[((size_t)((h << 6) + (n2 << 4) + l15) << 8) + (kk << 5) + (g << 3)];
        oc[n2] = __builtin_amdgcn_mfma_f32_16x16x32_bf16(pa.s, vb, oc[n2], 0, 0, 0);
      }
    }
    // lane holds ctx[q = 4g + r][d = 16*n2 + l15]
    #pragma unroll
    for (int n2 = 0; n2 < 4; ++n2)
      #pragma unroll
      for (int r = 0; r < 4; ++r)
        ctx[((size_t)b * 4096 + q0 + (w << 4) + (g << 2) + r) * 256 + (h << 6) + (n2 << 4) + l15]
            = f2b(oc[n2][r]);
  }
  #pragma unroll
  for (int nt = 0; nt < 16; ++nt)
    *(f32x4*)&am_out[(qw + l15) * 256 + (nt << 4) + (g << 2)] = am[nt];
}

extern "C" void kernel_launch(void* const* d_in, const int* in_sizes, int n_in,
                              void* d_out, int out_size, void* d_ws, size_t ws_size,
                              hipStream_t stream)
{
  const float* node_emb = (const float*)d_in[0];
  const float* cluster  = (const float*)d_in[1];
  const float* cw       = (const float*)d_in[2];
  const float* ln_q_g   = (const float*)d_in[3];
  const float* ln_q_b   = (const float*)d_in[4];
  const float* ln_kv_g  = (const float*)d_in[5];
  const float* ln_kv_b  = (const float*)d_in[6];
  const float* ln_o_g   = (const float*)d_in[7];
  const float* ln_o_b   = (const float*)d_in[8];
  const float* W_q  = (const float*)d_in[9];  const float* b_q  = (const float*)d_in[10];
  const float* W_k  = (const float*)d_in[11]; const float* b_k  = (const float*)d_in[12];
  const float* W_v  = (const float*)d_in[13]; const float* b_v  = (const float*)d_in[14];
  const float* W_o  = (const float*)d_in[15]; const float* b_o  = (const float*)d_in[16];
  const float* W_m1 = (const float*)d_in[17]; const float* b_m1 = (const float*)d_in[18];
  const float* W_m2 = (const float*)d_in[19]; const float* b_m2 = (const float*)d_in[20];

  char* ws = (char*)d_ws;
  short* Wbf  = (short*)ws;                                   // 786,432 B (6 x 64K bf16)
  short* n1   = (short*)(ws + 786432);                        // 16.78 MB: q_in -> ctx -> h1
  short* n2   = (short*)(ws + 786432 + 16777216);             // 16.78 MB: Q -> h_ln
  short* kvin = (short*)(ws + 786432 + 2 * 16777216);         // 1 MB
  short* Kb   = (short*)(ws + 786432 + 2 * 16777216 + 1048576);
  short* vt   = (short*)(ws + 786432 + 2 * 16777216 + 2 * 1048576);  // V^T, kv-permuted cols

  float* xbuf = (float*)d_out;            // first half: x, later overwritten by final out
  float* amof = (float*)d_out + 8388608;  // second half: attn_matrix

  cvt_w<<<1536, 256, 0, stream>>>(W_q, W_k, W_v, W_o, W_m1, W_m2, Wbf);
  ln_k<<<32768, 256, 0, stream>>>(node_emb, ln_q_g, ln_q_b, n1);
  ln_k<<<2048, 256, 0, stream>>>(cluster, ln_kv_g, ln_kv_b, kvin);
  // Q / K / V projections (V written transposed + kv-permuted into vt)
  gemmW<0,0,0,1,0,0><<<512, 256, 0, stream>>>(n1,   Wbf,          b_q, nullptr, nullptr, n2, nullptr, nullptr, nullptr);
  gemmW<0,0,0,1,0,0><<<32,  256, 0, stream>>>(kvin, Wbf + 65536,  b_k, nullptr, nullptr, Kb, nullptr, nullptr, nullptr);
  gemmW<0,0,0,1,1,0><<<32,  256, 0, stream>>>(kvin, Wbf + 131072, b_v, nullptr, nullptr, vt, nullptr, nullptr, nullptr);
  // attention (ctx -> n1, attn_matrix -> d_out 2nd half)
  attn_k<<<dim3(64, 8), 256, 0, stream>>>(n2, Kb, vt, cw, n1, amof);
  // O proj + residual -> x (f32) AND fused LN(x) -> n2 (bf16)
  gemmW<1,0,1,0,0,1><<<512, 256, 0, stream>>>(n1, Wbf + 196608, b_o, node_emb, xbuf, nullptr, ln_o_g, ln_o_b, n2);
  // MLP1 + GELU -> n1 ; MLP2 + residual(x) -> final out (in-place over x)
  gemmW<0,1,0,1,0,0><<<512, 256, 0, stream>>>(n2, Wbf + 262144, b_m1, nullptr, nullptr, n1, nullptr, nullptr, nullptr);
  gemmW<1,0,1,0,0,0><<<512, 256, 0, stream>>>(n1, Wbf + 327680, b_m2, xbuf, xbuf, nullptr, nullptr, nullptr, nullptr);
}

// Round 6
// 177.068 us; speedup vs baseline: 1.7539x; 1.3492x over previous
//
#include <hip/hip_runtime.h>
#include <math.h>

typedef __attribute__((ext_vector_type(8))) short short8;
typedef __attribute__((ext_vector_type(4))) float f32x4;

__device__ __forceinline__ float b2f(short s){
  return __uint_as_float(((unsigned int)(unsigned short)s) << 16);
}
__device__ __forceinline__ short f2b(float f){
  unsigned int u = __float_as_uint(f);
  u = (u + 0x7fffu + ((u >> 16) & 1u)) >> 16;
  return (short)u;
}
__device__ __forceinline__ unsigned pk2(float lo, float hi){
  return ((unsigned)(unsigned short)f2b(hi) << 16) | (unsigned)(unsigned short)f2b(lo);
}

// ---------------- weight f32 -> bf16 conversion ----------------
__global__ __launch_bounds__(256) void cvt_w(
    const float* __restrict__ s0, const float* __restrict__ s1,
    const float* __restrict__ s2, const float* __restrict__ s3,
    const float* __restrict__ s4, const float* __restrict__ s5,
    short* __restrict__ dst)
{
  const float* srcs[6] = {s0, s1, s2, s3, s4, s5};
  int i = blockIdx.x * 256 + threadIdx.x;       // 6*65536 total
  dst[i] = f2b(srcs[i >> 16][i & 65535]);
}

// ---------------- LayerNorm: f32 in, bf16 out (kv path only) ----------------
__global__ __launch_bounds__(256) void ln_k(
    const float* __restrict__ x, const float* __restrict__ g,
    const float* __restrict__ bta, short* __restrict__ y)
{
  const int row = blockIdx.x, t = threadIdx.x;
  const size_t base = (size_t)row * 256;
  float v = x[base + t];
  float s1 = v, s2 = v * v;
  #pragma unroll
  for (int off = 32; off; off >>= 1){ s1 += __shfl_down(s1, off); s2 += __shfl_down(s2, off); }
  __shared__ float a1[4], a2[4];
  __shared__ float mu_s, rs_s;
  if ((t & 63) == 0){ a1[t >> 6] = s1; a2[t >> 6] = s2; }
  __syncthreads();
  if (t == 0){
    float S1 = a1[0] + a1[1] + a1[2] + a1[3];
    float S2 = a2[0] + a2[1] + a2[2] + a2[3];
    float mu = S1 * 0.00390625f;
    float var = S2 * 0.00390625f - mu * mu;
    mu_s = mu; rs_s = rsqrtf(var + 1e-5f);
  }
  __syncthreads();
  y[base + t] = f2b((v - mu_s) * rs_s * g[t] + bta[t]);
}

// ---------------- wide GEMM: C[M,256] = A[M,256] @ W[256,256]^T + b ----------------
// Block = 64 rows x 256 cols, 4 waves (wave: 16 rows, acc[16] f32x4).
// A staged ONCE to LDS (optionally LayerNorm'd from f32 source: LNA).
// W double-buffered per 32-k-step: 1 barrier per step.
// Epilogue: GELU / f32 residual / f32 out / bf16 out / kfrag (OT=1) / vfrag (OT=2)
// / fused row-LN output.
template<int RES, int GELU, int OF, int OB, int OT, int LN, int LNA>
__global__ __launch_bounds__(256, 2) void gemmW(
    const short* __restrict__ A, const float* __restrict__ Af,
    const short* __restrict__ W,
    const float* __restrict__ bias, const float* __restrict__ res,
    float* __restrict__ outF, short* __restrict__ outB,
    const float* __restrict__ lng, const float* __restrict__ lnb,
    short* __restrict__ outL,
    const float* __restrict__ lnag, const float* __restrict__ lnab)
{
  __shared__ short As[64][264];        // full A tile, stride 528B (2-way banks on frag reads)
  __shared__ short Ws[2][256][40];     // k-slice double buffer
  const int tid = threadIdx.x;
  const int m0 = blockIdx.x << 6;
  const int w = tid >> 6, lane = tid & 63;
  const int l15 = lane & 15, g = lane >> 4;

  // ---- stage A (once) ----
  if (LNA){
    const int row = tid >> 2, c0 = (tid & 3) << 6;   // 4 threads/row, 64 cols each
    const float* src = &Af[(size_t)(m0 + row) * 256 + c0];
    float vv[64];
    #pragma unroll
    for (int i = 0; i < 16; ++i) *(f32x4*)&vv[4 * i] = *(const f32x4*)&src[4 * i];
    float s1 = 0.f, s2 = 0.f;
    #pragma unroll
    for (int i = 0; i < 64; ++i){ s1 += vv[i]; s2 += vv[i] * vv[i]; }
    s1 += __shfl_xor(s1, 1); s2 += __shfl_xor(s2, 1);
    s1 += __shfl_xor(s1, 2); s2 += __shfl_xor(s2, 2);
    const float mu = s1 * 0.00390625f;
    const float rs = rsqrtf(s2 * 0.00390625f - mu * mu + 1e-5f);
    #pragma unroll
    for (int i = 0; i < 8; ++i){
      f32x4 gv0 = *(const f32x4*)&lnag[c0 + 8 * i];
      f32x4 gv1 = *(const f32x4*)&lnag[c0 + 8 * i + 4];
      f32x4 bv0 = *(const f32x4*)&lnab[c0 + 8 * i];
      f32x4 bv1 = *(const f32x4*)&lnab[c0 + 8 * i + 4];
      short8 o;
      #pragma unroll
      for (int j = 0; j < 4; ++j) o[j] = f2b((vv[8 * i + j] - mu) * rs * gv0[j] + bv0[j]);
      #pragma unroll
      for (int j = 0; j < 4; ++j) o[4 + j] = f2b((vv[8 * i + 4 + j] - mu) * rs * gv1[j] + bv1[j]);
      *(short8*)&As[row][c0 + 8 * i] = o;
    }
  } else {
    #pragma unroll
    for (int it = 0; it < 8; ++it){
      int idx = tid + (it << 8);
      int row = idx >> 5, c = (idx & 31) << 3;
      *(short8*)&As[row][c] = *(const short8*)&A[(size_t)(m0 + row) * 256 + c];
    }
  }
  // ---- stage W k0=0 ----
  #pragma unroll
  for (int it = 0; it < 4; ++it){
    int row = (it << 6) + (tid >> 2), c = (tid & 3) << 3;
    *(short8*)&Ws[0][row][c] = *(const short8*)&W[(size_t)row * 256 + c];
  }
  __syncthreads();

  f32x4 acc[16];
  #pragma unroll
  for (int nt = 0; nt < 16; ++nt) acc[nt] = {0.f, 0.f, 0.f, 0.f};

  int cur = 0;
  for (int s = 0; s < 8; ++s){
    const int k0 = s << 5;
    short8 wreg[4];
    if (s < 7){
      #pragma unroll
      for (int it = 0; it < 4; ++it)
        wreg[it] = *(const short8*)&W[(size_t)((it << 6) + (tid >> 2)) * 256 + k0 + 32 + ((tid & 3) << 3)];
    }
    short8 af = *(const short8*)&As[(w << 4) + l15][k0 + (g << 3)];
    #pragma unroll
    for (int nt = 0; nt < 16; ++nt){
      short8 bf = *(const short8*)&Ws[cur][(nt << 4) + l15][g << 3];
      acc[nt] = __builtin_amdgcn_mfma_f32_16x16x32_bf16(af, bf, acc[nt], 0, 0, 0);
    }
    if (s < 7){
      #pragma unroll
      for (int it = 0; it < 4; ++it)
        *(short8*)&Ws[cur ^ 1][(it << 6) + (tid >> 2)][(tid & 3) << 3] = wreg[it];
    }
    __syncthreads();
    cur ^= 1;
  }

  const int row_l = (w << 4) + (g << 2);     // + r = wave's row within block
  #pragma unroll
  for (int nt = 0; nt < 16; ++nt){
    const int col = (nt << 4) + l15;
    const float bv = bias[col];
    #pragma unroll
    for (int r = 0; r < 4; ++r){
      const int m = m0 + row_l + r;
      const size_t idx = (size_t)m * 256 + col;
      float v = acc[nt][r] + bv;
      if (GELU) v = 0.5f * v * (1.0f + erff(v * 0.70710678118f));
      if (RES) v += res[idx];
      if (OF) outF[idx] = v;
      acc[nt][r] = v;
      if (OB) outB[idx] = f2b(v);
      if (OT == 1){   // kfrag: [b][h][nt][half][g][l15][8]
        const int b_ = m >> 8, kvr = m & 255;
        const int knt = kvr >> 4, kl = kvr & 15;
        const int h = col >> 6, half = (col >> 5) & 1, kg = (col >> 3) & 3, kj = col & 7;
        outB[(((((size_t)(b_ * 4 + h) * 16 + knt) * 2 + half) * 4 + kg) * 16 + kl) * 8 + kj] = f2b(v);
      }
      if (OT == 2){   // vfrag: [b][h][kk][n2][g][l15][8]
        const int b_ = m >> 8, kvj = m & 255;
        const int jp = (kvj & ~31) | (((kvj >> 2) & 3) << 3) | (((kvj >> 4) & 1) << 2) | (kvj & 3);
        const int h = col >> 6, dp = col & 63;
        const int kk = jp >> 5, vg = (jp >> 3) & 3, vj = jp & 7;
        const int vn2 = dp >> 4, vl = dp & 15;
        outB[(((((size_t)(b_ * 4 + h) * 8 + kk) * 4 + vn2) * 4 + vg) * 16 + vl) * 8 + vj] = f2b(v);
      }
    }
  }
  if (LN){
    #pragma unroll
    for (int r = 0; r < 4; ++r){
      float s1 = 0.f, s2 = 0.f;
      #pragma unroll
      for (int nt = 0; nt < 16; ++nt){ float v = acc[nt][r]; s1 += v; s2 += v * v; }
      #pragma unroll
      for (int off = 1; off < 16; off <<= 1){ s1 += __shfl_xor(s1, off); s2 += __shfl_xor(s2, off); }
      const float mu = s1 * 0.00390625f;
      const float rs = rsqrtf(s2 * 0.00390625f - mu * mu + 1e-5f);
      #pragma unroll
      for (int nt = 0; nt < 16; ++nt){
        const int col = (nt << 4) + l15;
        outL[(size_t)(m0 + row_l + r) * 256 + col] =
            f2b((acc[nt][r] - mu) * rs * lng[col] + lnb[col]);
      }
    }
  }
}

// ---------------- fused MFMA attention: LDS-free, barrier-free, coalesced ----------------
// Block: 64 q-rows, 4 independent waves (16 q-rows each), all 4 heads.
// K/V pre-scattered into fragment-order buffers by the K/V GEMM epilogues:
// every B-operand load here is base + lane*16B (fully coalesced, L2-resident).
// Swapped QK^T: lane(l15,g) holds P[q=l15][kv=16nt+4g+r]; softmax in-lane;
// PV A-frags are in-lane bf16 packs (kv-permutation baked into vfrag).
__global__ __launch_bounds__(256, 2) void attn_k(
    const short* __restrict__ Qb, const short* __restrict__ Kf,
    const short* __restrict__ Vf, const float* __restrict__ cw,
    short* __restrict__ ctx, float* __restrict__ am_out)
{
  const int b = blockIdx.y;
  const int q0 = blockIdx.x << 6;
  const int tid = threadIdx.x;
  const int w = tid >> 6, lane = tid & 63;
  const int l15 = lane & 15, g = lane >> 4;
  const size_t qw = (size_t)b * 4096 + q0 + (w << 4);   // wave's first q row

  // clustering weights (bf16-packed) + attn_matrix accumulator, in registers.
  unsigned cwp[16][2];
  f32x4 am[16];
  #pragma unroll
  for (int nt = 0; nt < 16; ++nt){
    f32x4 c = *(const f32x4*)&cw[(qw + l15) * 256 + (nt << 4) + (g << 2)];
    cwp[nt][0] = pk2(c[0], c[1]);
    cwp[nt][1] = pk2(c[2], c[3]);
    am[nt] = {0.f, 0.f, 0.f, 0.f};
  }

  for (int h = 0; h < 4; ++h){
    const short* kh = Kf + (((size_t)(b * 4 + h)) << 14);   // 16nt*2half*512
    const short* vh = Vf + (((size_t)(b * 4 + h)) << 14);   // 8kk*4n2*512
    short8 qf0 = *(const short8*)&Qb[(qw + l15) * 256 + (h << 6) + (g << 3)];
    short8 qf1 = *(const short8*)&Qb[(qw + l15) * 256 + (h << 6) + 32 + (g << 3)];

    // ---- scores: coalesced K-frag loads ----
    f32x4 acc[16];
    #pragma unroll
    for (int nt = 0; nt < 16; ++nt) acc[nt] = {0.f, 0.f, 0.f, 0.f};
    #pragma unroll
    for (int nt = 0; nt < 16; ++nt){
      short8 kf0 = *(const short8*)&kh[(nt << 10) + (lane << 3)];
      acc[nt] = __builtin_amdgcn_mfma_f32_16x16x32_bf16(kf0, qf0, acc[nt], 0, 0, 0);
      short8 kf1 = *(const short8*)&kh[(nt << 10) + 512 + (lane << 3)];
      acc[nt] = __builtin_amdgcn_mfma_f32_16x16x32_bf16(kf1, qf1, acc[nt], 0, 0, 0);
    }
    // ---- softmax, fully in-lane (row q = l15; partners at lane^16, lane^32) ----
    float mx = -3.4e38f;
    #pragma unroll
    for (int nt = 0; nt < 16; ++nt){
      float c0 = __uint_as_float(cwp[nt][0] << 16);
      float c1 = __uint_as_float(cwp[nt][0] & 0xffff0000u);
      float c2 = __uint_as_float(cwp[nt][1] << 16);
      float c3 = __uint_as_float(cwp[nt][1] & 0xffff0000u);
      acc[nt][0] = acc[nt][0] * 0.125f + c0;
      acc[nt][1] = acc[nt][1] * 0.125f + c1;
      acc[nt][2] = acc[nt][2] * 0.125f + c2;
      acc[nt][3] = acc[nt][3] * 0.125f + c3;
      mx = fmaxf(mx, fmaxf(fmaxf(acc[nt][0], acc[nt][1]), fmaxf(acc[nt][2], acc[nt][3])));
    }
    mx = fmaxf(mx, __shfl_xor(mx, 16));
    mx = fmaxf(mx, __shfl_xor(mx, 32));
    float sm = 0.f;
    #pragma unroll
    for (int nt = 0; nt < 16; ++nt){
      #pragma unroll
      for (int r = 0; r < 4; ++r){
        float e = __expf(acc[nt][r] - mx);
        acc[nt][r] = e; sm += e;
      }
    }
    sm += __shfl_xor(sm, 16);
    sm += __shfl_xor(sm, 32);
    float inv = 1.f / sm;
    #pragma unroll
    for (int nt = 0; nt < 16; ++nt){
      #pragma unroll
      for (int r = 0; r < 4; ++r){
        float p = acc[nt][r] * inv;
        acc[nt][r] = p;
        am[nt][r] += 0.25f * p;
      }
    }
    // ---- ctx = P @ V : in-lane A packs; coalesced V-frag loads ----
    f32x4 oc[4] = {{0,0,0,0},{0,0,0,0},{0,0,0,0},{0,0,0,0}};
    #pragma unroll
    for (int kk = 0; kk < 8; ++kk){
      union { short8 s; unsigned u[4]; } pa;
      pa.u[0] = pk2(acc[2 * kk][0],     acc[2 * kk][1]);
      pa.u[1] = pk2(acc[2 * kk][2],     acc[2 * kk][3]);
      pa.u[2] = pk2(acc[2 * kk + 1][0], acc[2 * kk + 1][1]);
      pa.u[3] = pk2(acc[2 * kk + 1][2], acc[2 * kk + 1][3]);
      #pragma unroll
      for (int n2 = 0; n2 < 4; ++n2){
        short8 vb = *(const short8*)&vh[(((kk << 2) + n2) << 9) + (lane << 3)];
        oc[n2] = __builtin_amdgcn_mfma_f32_16x16x32_bf16(pa.s, vb, oc[n2], 0, 0, 0);
      }
    }
    // lane holds ctx[q = 4g + r][d = 16*n2 + l15]
    #pragma unroll
    for (int n2 = 0; n2 < 4; ++n2)
      #pragma unroll
      for (int r = 0; r < 4; ++r)
        ctx[((size_t)b * 4096 + q0 + (w << 4) + (g << 2) + r) * 256 + (h << 6) + (n2 << 4) + l15]
            = f2b(oc[n2][r]);
  }
  #pragma unroll
  for (int nt = 0; nt < 16; ++nt)
    *(f32x4*)&am_out[(qw + l15) * 256 + (nt << 4) + (g << 2)] = am[nt];
}

extern "C" void kernel_launch(void* const* d_in, const int* in_sizes, int n_in,
                              void* d_out, int out_size, void* d_ws, size_t ws_size,
                              hipStream_t stream)
{
  const float* node_emb = (const float*)d_in[0];
  const float* cluster  = (const float*)d_in[1];
  const float* cw       = (const float*)d_in[2];
  const float* ln_q_g   = (const float*)d_in[3];
  const float* ln_q_b   = (const float*)d_in[4];
  const float* ln_kv_g  = (const float*)d_in[5];
  const float* ln_kv_b  = (const float*)d_in[6];
  const float* ln_o_g   = (const float*)d_in[7];
  const float* ln_o_b   = (const float*)d_in[8];
  const float* W_q  = (const float*)d_in[9];  const float* b_q  = (const float*)d_in[10];
  const float* W_k  = (const float*)d_in[11]; const float* b_k  = (const float*)d_in[12];
  const float* W_v  = (const float*)d_in[13]; const float* b_v  = (const float*)d_in[14];
  const float* W_o  = (const float*)d_in[15]; const float* b_o  = (const float*)d_in[16];
  const float* W_m1 = (const float*)d_in[17]; const float* b_m1 = (const float*)d_in[18];
  const float* W_m2 = (const float*)d_in[19]; const float* b_m2 = (const float*)d_in[20];

  char* ws = (char*)d_ws;
  short* Wbf   = (short*)ws;                                   // 786,432 B (6 x 64K bf16)
  short* n1    = (short*)(ws + 786432);                        // 16.78 MB: ctx -> h1
  short* n2    = (short*)(ws + 786432 + 16777216);             // 16.78 MB: Q -> h_ln
  short* kvin  = (short*)(ws + 786432 + 2 * 16777216);         // 1 MB
  short* kfrag = (short*)(ws + 786432 + 2 * 16777216 + 1048576);
  short* vfrag = (short*)(ws + 786432 + 2 * 16777216 + 2 * 1048576);

  float* xbuf = (float*)d_out;            // first half: x, later overwritten by final out
  float* amof = (float*)d_out + 8388608;  // second half: attn_matrix

  cvt_w<<<1536, 256, 0, stream>>>(W_q, W_k, W_v, W_o, W_m1, W_m2, Wbf);
  ln_k<<<2048, 256, 0, stream>>>(cluster, ln_kv_g, ln_kv_b, kvin);
  // Q projection with fused input-LayerNorm (reads node_emb f32 directly)
  gemmW<0,0,0,1,0,0,1><<<512, 256, 0, stream>>>(nullptr, node_emb, Wbf, b_q, nullptr,
      nullptr, n2, nullptr, nullptr, nullptr, ln_q_g, ln_q_b);
  // K / V projections -> fragment-order buffers
  gemmW<0,0,0,0,1,0,0><<<32, 256, 0, stream>>>(kvin, nullptr, Wbf + 65536, b_k, nullptr,
      nullptr, kfrag, nullptr, nullptr, nullptr, nullptr, nullptr);
  gemmW<0,0,0,0,2,0,0><<<32, 256, 0, stream>>>(kvin, nullptr, Wbf + 131072, b_v, nullptr,
      nullptr, vfrag, nullptr, nullptr, nullptr, nullptr, nullptr);
  // attention (ctx -> n1, attn_matrix -> d_out 2nd half)
  attn_k<<<dim3(64, 8), 256, 0, stream>>>(n2, kfrag, vfrag, cw, n1, amof);
  // O proj + residual -> x (f32) AND fused LN(x) -> n2 (bf16)
  gemmW<1,0,1,0,0,1,0><<<512, 256, 0, stream>>>(n1, nullptr, Wbf + 196608, b_o, node_emb,
      xbuf, nullptr, ln_o_g, ln_o_b, n2, nullptr, nullptr);
  // MLP1 + GELU -> n1 ; MLP2 + residual(x) -> final out (in-place over x)
  gemmW<0,1,0,1,0,0,0><<<512, 256, 0, stream>>>(n2, nullptr, Wbf + 262144, b_m1, nullptr,
      nullptr, n1, nullptr, nullptr, nullptr, nullptr, nullptr);
  gemmW<1,0,1,0,0,0,0><<<512, 256, 0, stream>>>(n1, nullptr, Wbf + 327680, b_m2, xbuf,
      xbuf, nullptr, nullptr, nullptr, nullptr, nullptr, nullptr);
}

// Round 7
// 174.810 us; speedup vs baseline: 1.7765x; 1.0129x over previous
//
#include <hip/hip_runtime.h>
#include <math.h>

typedef __attribute__((ext_vector_type(8))) short short8;
typedef __attribute__((ext_vector_type(4))) float f32x4;

__device__ __forceinline__ float b2f(short s){
  return __uint_as_float(((unsigned int)(unsigned short)s) << 16);
}
__device__ __forceinline__ short f2b(float f){
  unsigned int u = __float_as_uint(f);
  u = (u + 0x7fffu + ((u >> 16) & 1u)) >> 16;
  return (short)u;
}
__device__ __forceinline__ unsigned pk2(float lo, float hi){
  return ((unsigned)(unsigned short)f2b(hi) << 16) | (unsigned)(unsigned short)f2b(lo);
}

// ---------------- weight f32 -> bf16 conversion ----------------
__global__ __launch_bounds__(256) void cvt_w(
    const float* __restrict__ s0, const float* __restrict__ s1,
    const float* __restrict__ s2, const float* __restrict__ s3,
    const float* __restrict__ s4, const float* __restrict__ s5,
    short* __restrict__ dst)
{
  const float* srcs[6] = {s0, s1, s2, s3, s4, s5};
  int i = blockIdx.x * 256 + threadIdx.x;       // 6*65536 total
  dst[i] = f2b(srcs[i >> 16][i & 65535]);
}

// ---------------- LayerNorm: f32 in, bf16 out (kv path only) ----------------
__global__ __launch_bounds__(256) void ln_k(
    const float* __restrict__ x, const float* __restrict__ g,
    const float* __restrict__ bta, short* __restrict__ y)
{
  const int row = blockIdx.x, t = threadIdx.x;
  const size_t base = (size_t)row * 256;
  float v = x[base + t];
  float s1 = v, s2 = v * v;
  #pragma unroll
  for (int off = 32; off; off >>= 1){ s1 += __shfl_down(s1, off); s2 += __shfl_down(s2, off); }
  __shared__ float a1[4], a2[4];
  __shared__ float mu_s, rs_s;
  if ((t & 63) == 0){ a1[t >> 6] = s1; a2[t >> 6] = s2; }
  __syncthreads();
  if (t == 0){
    float S1 = a1[0] + a1[1] + a1[2] + a1[3];
    float S2 = a2[0] + a2[1] + a2[2] + a2[3];
    float mu = S1 * 0.00390625f;
    float var = S2 * 0.00390625f - mu * mu;
    mu_s = mu; rs_s = rsqrtf(var + 1e-5f);
  }
  __syncthreads();
  y[base + t] = f2b((v - mu_s) * rs_s * g[t] + bta[t]);
}

// ---------------- wide GEMM: C[M,256] = A[M,256] @ W[256,256]^T + b ----------------
// Block = 64 rows x 256 cols, 4 waves (wave: 16 rows, acc[16] f32x4).
// A staged ONCE to LDS; optionally LayerNorm'd in the prologue:
//   LNA=1: A is f32 (Af) + LN ; LNA=2: A is bf16 + LN.
// W double-buffered per 32-k-step (1 barrier/step).
// Epilogue: GELU / residual (RES=1 f32, RES=2 bf16) / f32 out / bf16 out /
//           kfrag (OT=1) / vfrag (OT=2).
template<int RES, int GELU, int OF, int OB, int OT, int LNA>
__global__ __launch_bounds__(256, 2) void gemmW(
    const short* __restrict__ A, const float* __restrict__ Af,
    const short* __restrict__ W,
    const float* __restrict__ bias,
    const float* __restrict__ resF, const short* __restrict__ resB,
    float* __restrict__ outF, short* __restrict__ outB,
    const float* __restrict__ lnag, const float* __restrict__ lnab)
{
  __shared__ short As[64][264];        // full A tile
  __shared__ short Ws[2][256][40];     // k-slice double buffer
  const int tid = threadIdx.x;
  const int m0 = blockIdx.x << 6;
  const int w = tid >> 6, lane = tid & 63;
  const int l15 = lane & 15, g = lane >> 4;

  // ---- stage A (once), optionally LayerNorm'd ----
  if (LNA){
    const int row = tid >> 2, c0 = (tid & 3) << 6;   // 4 threads/row, 64 cols each
    float vv[64];
    if (LNA == 1){
      const float* src = &Af[(size_t)(m0 + row) * 256 + c0];
      #pragma unroll
      for (int i = 0; i < 16; ++i) *(f32x4*)&vv[4 * i] = *(const f32x4*)&src[4 * i];
    } else {
      const short* src = &A[(size_t)(m0 + row) * 256 + c0];
      #pragma unroll
      for (int i = 0; i < 8; ++i){
        short8 s = *(const short8*)&src[8 * i];
        #pragma unroll
        for (int j = 0; j < 8; ++j) vv[8 * i + j] = b2f(s[j]);
      }
    }
    float s1 = 0.f, s2 = 0.f;
    #pragma unroll
    for (int i = 0; i < 64; ++i){ s1 += vv[i]; s2 += vv[i] * vv[i]; }
    s1 += __shfl_xor(s1, 1); s2 += __shfl_xor(s2, 1);
    s1 += __shfl_xor(s1, 2); s2 += __shfl_xor(s2, 2);
    const float mu = s1 * 0.00390625f;
    const float rs = rsqrtf(s2 * 0.00390625f - mu * mu + 1e-5f);
    #pragma unroll
    for (int i = 0; i < 8; ++i){
      f32x4 gv0 = *(const f32x4*)&lnag[c0 + 8 * i];
      f32x4 gv1 = *(const f32x4*)&lnag[c0 + 8 * i + 4];
      f32x4 bv0 = *(const f32x4*)&lnab[c0 + 8 * i];
      f32x4 bv1 = *(const f32x4*)&lnab[c0 + 8 * i + 4];
      short8 o;
      #pragma unroll
      for (int j = 0; j < 4; ++j) o[j] = f2b((vv[8 * i + j] - mu) * rs * gv0[j] + bv0[j]);
      #pragma unroll
      for (int j = 0; j < 4; ++j) o[4 + j] = f2b((vv[8 * i + 4 + j] - mu) * rs * gv1[j] + bv1[j]);
      *(short8*)&As[row][c0 + 8 * i] = o;
    }
  } else {
    #pragma unroll
    for (int it = 0; it < 8; ++it){
      int idx = tid + (it << 8);
      int row = idx >> 5, c = (idx & 31) << 3;
      *(short8*)&As[row][c] = *(const short8*)&A[(size_t)(m0 + row) * 256 + c];
    }
  }
  // ---- stage W k0=0 ----
  #pragma unroll
  for (int it = 0; it < 4; ++it){
    int row = (it << 6) + (tid >> 2), c = (tid & 3) << 3;
    *(short8*)&Ws[0][row][c] = *(const short8*)&W[(size_t)row * 256 + c];
  }
  __syncthreads();

  f32x4 acc[16];
  #pragma unroll
  for (int nt = 0; nt < 16; ++nt) acc[nt] = {0.f, 0.f, 0.f, 0.f};

  int cur = 0;
  for (int s = 0; s < 8; ++s){
    const int k0 = s << 5;
    short8 wreg[4];
    if (s < 7){
      #pragma unroll
      for (int it = 0; it < 4; ++it)
        wreg[it] = *(const short8*)&W[(size_t)((it << 6) + (tid >> 2)) * 256 + k0 + 32 + ((tid & 3) << 3)];
    }
    short8 af = *(const short8*)&As[(w << 4) + l15][k0 + (g << 3)];
    #pragma unroll
    for (int nt = 0; nt < 16; ++nt){
      short8 bf = *(const short8*)&Ws[cur][(nt << 4) + l15][g << 3];
      acc[nt] = __builtin_amdgcn_mfma_f32_16x16x32_bf16(af, bf, acc[nt], 0, 0, 0);
    }
    if (s < 7){
      #pragma unroll
      for (int it = 0; it < 4; ++it)
        *(short8*)&Ws[cur ^ 1][(it << 6) + (tid >> 2)][(tid & 3) << 3] = wreg[it];
    }
    __syncthreads();
    cur ^= 1;
  }

  const int row_l = (w << 4) + (g << 2);     // + r = wave's row within block
  #pragma unroll
  for (int nt = 0; nt < 16; ++nt){
    const int col = (nt << 4) + l15;
    const float bv = bias[col];
    #pragma unroll
    for (int r = 0; r < 4; ++r){
      const int m = m0 + row_l + r;
      const size_t idx = (size_t)m * 256 + col;
      float v = acc[nt][r] + bv;
      if (GELU) v = 0.5f * v * (1.0f + erff(v * 0.70710678118f));
      if (RES == 1) v += resF[idx];
      if (RES == 2) v += b2f(resB[idx]);
      if (OF) outF[idx] = v;
      if (OB) outB[idx] = f2b(v);
      if (OT == 1){   // kfrag: [b][h][nt][half][g][l15][8]
        const int b_ = m >> 8, kvr = m & 255;
        const int knt = kvr >> 4, kl = kvr & 15;
        const int h = col >> 6, half = (col >> 5) & 1, kg = (col >> 3) & 3, kj = col & 7;
        outB[(((((size_t)(b_ * 4 + h) * 16 + knt) * 2 + half) * 4 + kg) * 16 + kl) * 8 + kj] = f2b(v);
      }
      if (OT == 2){   // vfrag: [b][h][kk][n2][g][l15][8]
        const int b_ = m >> 8, kvj = m & 255;
        const int jp = (kvj & ~31) | (((kvj >> 2) & 3) << 3) | (((kvj >> 4) & 1) << 2) | (kvj & 3);
        const int h = col >> 6, dp = col & 63;
        const int kk = jp >> 5, vg = (jp >> 3) & 3, vj = jp & 7;
        const int vn2 = dp >> 4, vl = dp & 15;
        outB[(((((size_t)(b_ * 4 + h) * 8 + kk) * 4 + vn2) * 4 + vg) * 16 + vl) * 8 + vj] = f2b(v);
      }
    }
  }
}

// ---------------- fused MFMA attention: head-split, 4x parallelism ----------------
// Block: 16 q-rows, 4 waves; wave w owns head h=w (whole kv range).
// cw + Q staged coalesced into LDS; K/V frag buffers coalesced from L2.
// Swapped QK^T: lane(l15,g) holds P[q=l15][kv=16nt+4g+r]; softmax in-lane
// (cw read from LDS); PV via kv-permuted vfrag; attn_matrix = mean over heads
// computed by a deterministic 4-phase serialized LDS reduction.
__global__ __launch_bounds__(256, 4) void attn_k(
    const short* __restrict__ Qb, const short* __restrict__ Kf,
    const short* __restrict__ Vf, const float* __restrict__ cw,
    short* __restrict__ ctx, float* __restrict__ am_out)
{
  __shared__ float cwb[16][257];   // cw, then reused as the am accumulator
  __shared__ short Qs[16][264];
  const int b = blockIdx.y;
  const int q0 = blockIdx.x << 4;
  const int tid = threadIdx.x;
  const int w = tid >> 6, lane = tid & 63;   // w = head
  const int l15 = lane & 15, g = lane >> 4;
  const size_t qrow0 = (size_t)b * 4096 + q0;

  // stage cw (16 x 256 f32) coalesced
  #pragma unroll
  for (int i = 0; i < 4; ++i){
    int f = (tid << 2) + (i << 10);
    *(f32x4*)&cwb[f >> 8][f & 255] = *(const f32x4*)&cw[(qrow0 + (f >> 8)) * 256 + (f & 255)];
  }
  // stage Q (16 x 256 bf16) coalesced
  #pragma unroll
  for (int i = 0; i < 2; ++i){
    int f = (tid << 3) + (i << 11);
    *(short8*)&Qs[f >> 8][f & 255] = *(const short8*)&Qb[(qrow0 + (f >> 8)) * 256 + (f & 255)];
  }
  __syncthreads();

  const short* kh = Kf + (((size_t)(b * 4 + w)) << 14);
  const short* vh = Vf + (((size_t)(b * 4 + w)) << 14);
  short8 qf0 = *(const short8*)&Qs[l15][(w << 6) + (g << 3)];
  short8 qf1 = *(const short8*)&Qs[l15][(w << 6) + 32 + (g << 3)];

  // ---- scores ----
  f32x4 acc[16];
  #pragma unroll
  for (int nt = 0; nt < 16; ++nt) acc[nt] = {0.f, 0.f, 0.f, 0.f};
  #pragma unroll
  for (int nt = 0; nt < 16; ++nt){
    short8 kf0 = *(const short8*)&kh[(nt << 10) + (lane << 3)];
    acc[nt] = __builtin_amdgcn_mfma_f32_16x16x32_bf16(kf0, qf0, acc[nt], 0, 0, 0);
    short8 kf1 = *(const short8*)&kh[(nt << 10) + 512 + (lane << 3)];
    acc[nt] = __builtin_amdgcn_mfma_f32_16x16x32_bf16(kf1, qf1, acc[nt], 0, 0, 0);
  }
  // ---- softmax, in-lane; cw from LDS ----
  float mx = -3.4e38f;
  #pragma unroll
  for (int nt = 0; nt < 16; ++nt){
    f32x4 c = *(const f32x4*)&cwb[l15][(nt << 4) + (g << 2)];
    acc[nt][0] = acc[nt][0] * 0.125f + c[0];
    acc[nt][1] = acc[nt][1] * 0.125f + c[1];
    acc[nt][2] = acc[nt][2] * 0.125f + c[2];
    acc[nt][3] = acc[nt][3] * 0.125f + c[3];
    mx = fmaxf(mx, fmaxf(fmaxf(acc[nt][0], acc[nt][1]), fmaxf(acc[nt][2], acc[nt][3])));
  }
  mx = fmaxf(mx, __shfl_xor(mx, 16));
  mx = fmaxf(mx, __shfl_xor(mx, 32));
  float sm = 0.f;
  #pragma unroll
  for (int nt = 0; nt < 16; ++nt){
    #pragma unroll
    for (int r = 0; r < 4; ++r){
      float e = __expf(acc[nt][r] - mx);
      acc[nt][r] = e; sm += e;
    }
  }
  sm += __shfl_xor(sm, 16);
  sm += __shfl_xor(sm, 32);
  float inv = 1.f / sm;
  #pragma unroll
  for (int nt = 0; nt < 16; ++nt){
    acc[nt][0] *= inv; acc[nt][1] *= inv; acc[nt][2] *= inv; acc[nt][3] *= inv;
  }
  // ---- ctx = P @ V ----
  f32x4 oc[4] = {{0,0,0,0},{0,0,0,0},{0,0,0,0},{0,0,0,0}};
  #pragma unroll
  for (int kk = 0; kk < 8; ++kk){
    union { short8 s; unsigned u[4]; } pa;
    pa.u[0] = pk2(acc[2 * kk][0],     acc[2 * kk][1]);
    pa.u[1] = pk2(acc[2 * kk][2],     acc[2 * kk][3]);
    pa.u[2] = pk2(acc[2 * kk + 1][0], acc[2 * kk + 1][1]);
    pa.u[3] = pk2(acc[2 * kk + 1][2], acc[2 * kk + 1][3]);
    #pragma unroll
    for (int n2 = 0; n2 < 4; ++n2){
      short8 vb = *(const short8*)&vh[(((kk << 2) + n2) << 9) + (lane << 3)];
      oc[n2] = __builtin_amdgcn_mfma_f32_16x16x32_bf16(pa.s, vb, oc[n2], 0, 0, 0);
    }
  }
  #pragma unroll
  for (int n2 = 0; n2 < 4; ++n2)
    #pragma unroll
    for (int r = 0; r < 4; ++r)
      ctx[(qrow0 + (g << 2) + r) * 256 + (w << 6) + (n2 << 4) + l15] = f2b(oc[n2][r]);

  // ---- attn_matrix: deterministic serialized cross-head reduce in LDS ----
  __syncthreads();                 // all waves done reading cwb
  #pragma unroll
  for (int ww = 0; ww < 4; ++ww){
    if (w == ww){
      #pragma unroll
      for (int nt = 0; nt < 16; ++nt){
        float* p = &cwb[l15][(nt << 4) + (g << 2)];
        if (ww == 0){
          f32x4 o = {0.25f * acc[nt][0], 0.25f * acc[nt][1],
                     0.25f * acc[nt][2], 0.25f * acc[nt][3]};
          *(f32x4*)p = o;
        } else {
          f32x4 cu = *(const f32x4*)p;
          cu[0] += 0.25f * acc[nt][0]; cu[1] += 0.25f * acc[nt][1];
          cu[2] += 0.25f * acc[nt][2]; cu[3] += 0.25f * acc[nt][3];
          *(f32x4*)p = cu;
        }
      }
    }
    __syncthreads();
  }
  #pragma unroll
  for (int i = 0; i < 4; ++i){
    int f = (tid << 2) + (i << 10);
    *(f32x4*)&am_out[(qrow0 + (f >> 8)) * 256 + (f & 255)] = *(const f32x4*)&cwb[f >> 8][f & 255];
  }
}

extern "C" void kernel_launch(void* const* d_in, const int* in_sizes, int n_in,
                              void* d_out, int out_size, void* d_ws, size_t ws_size,
                              hipStream_t stream)
{
  const float* node_emb = (const float*)d_in[0];
  const float* cluster  = (const float*)d_in[1];
  const float* cw       = (const float*)d_in[2];
  const float* ln_q_g   = (const float*)d_in[3];
  const float* ln_q_b   = (const float*)d_in[4];
  const float* ln_kv_g  = (const float*)d_in[5];
  const float* ln_kv_b  = (const float*)d_in[6];
  const float* ln_o_g   = (const float*)d_in[7];
  const float* ln_o_b   = (const float*)d_in[8];
  const float* W_q  = (const float*)d_in[9];  const float* b_q  = (const float*)d_in[10];
  const float* W_k  = (const float*)d_in[11]; const float* b_k  = (const float*)d_in[12];
  const float* W_v  = (const float*)d_in[13]; const float* b_v  = (const float*)d_in[14];
  const float* W_o  = (const float*)d_in[15]; const float* b_o  = (const float*)d_in[16];
  const float* W_m1 = (const float*)d_in[17]; const float* b_m1 = (const float*)d_in[18];
  const float* W_m2 = (const float*)d_in[19]; const float* b_m2 = (const float*)d_in[20];

  char* ws = (char*)d_ws;
  short* Wbf   = (short*)ws;                                   // 786,432 B (6 x 64K bf16)
  short* n1    = (short*)(ws + 786432);                        // 16.78 MB: ctx -> h1
  short* n2    = (short*)(ws + 786432 + 16777216);             // 16.78 MB: Q -> x (bf16)
  short* kvin  = (short*)(ws + 786432 + 2 * 16777216);         // 1 MB
  short* kfrag = (short*)(ws + 786432 + 2 * 16777216 + 1048576);
  short* vfrag = (short*)(ws + 786432 + 2 * 16777216 + 2 * 1048576);

  float* outF = (float*)d_out;            // first half: final out (written only by M2)
  float* amof = (float*)d_out + 8388608;  // second half: attn_matrix

  cvt_w<<<1536, 256, 0, stream>>>(W_q, W_k, W_v, W_o, W_m1, W_m2, Wbf);
  ln_k<<<2048, 256, 0, stream>>>(cluster, ln_kv_g, ln_kv_b, kvin);
  // Q projection with fused input-LayerNorm (reads node_emb f32 directly)
  gemmW<0,0,0,1,0,1><<<512, 256, 0, stream>>>(nullptr, node_emb, Wbf, b_q,
      nullptr, nullptr, nullptr, n2, ln_q_g, ln_q_b);
  // K / V projections -> fragment-order buffers
  gemmW<0,0,0,0,1,0><<<32, 256, 0, stream>>>(kvin, nullptr, Wbf + 65536, b_k,
      nullptr, nullptr, nullptr, kfrag, nullptr, nullptr);
  gemmW<0,0,0,0,2,0><<<32, 256, 0, stream>>>(kvin, nullptr, Wbf + 131072, b_v,
      nullptr, nullptr, nullptr, vfrag, nullptr, nullptr);
  // attention (ctx -> n1, attn_matrix -> d_out 2nd half)
  attn_k<<<dim3(256, 8), 256, 0, stream>>>(n2, kfrag, vfrag, cw, n1, amof);
  // O proj + residual(node_emb f32) -> x as bf16 into n2 (Q dead)
  gemmW<1,0,0,1,0,0><<<512, 256, 0, stream>>>(n1, nullptr, Wbf + 196608, b_o,
      node_emb, nullptr, nullptr, n2, nullptr, nullptr);
  // MLP1 with fused LN(x) prologue + GELU -> n1
  gemmW<0,1,0,1,0,2><<<512, 256, 0, stream>>>(n2, nullptr, Wbf + 262144, b_m1,
      nullptr, nullptr, nullptr, n1, ln_o_g, ln_o_b);
  // MLP2 + residual(x bf16) -> final out f32
  gemmW<2,0,1,0,0,0><<<512, 256, 0, stream>>>(n1, nullptr, Wbf + 327680, b_m2,
      nullptr, n2, outF, nullptr, nullptr, nullptr);
}

// Round 8
// 147.026 us; speedup vs baseline: 2.1122x; 1.1890x over previous
//
#include <hip/hip_runtime.h>
#include <math.h>

typedef __attribute__((ext_vector_type(8))) short short8;
typedef __attribute__((ext_vector_type(4))) float f32x4;

#define AS1 __attribute__((address_space(1)))
#define AS3 __attribute__((address_space(3)))

__device__ __forceinline__ float b2f(short s){
  return __uint_as_float(((unsigned int)(unsigned short)s) << 16);
}
__device__ __forceinline__ short f2b(float f){
  unsigned int u = __float_as_uint(f);
  u = (u + 0x7fffu + ((u >> 16) & 1u)) >> 16;
  return (short)u;
}
__device__ __forceinline__ unsigned pk2(float lo, float hi){
  return ((unsigned)(unsigned short)f2b(hi) << 16) | (unsigned)(unsigned short)f2b(lo);
}

// ---------------- weight f32 -> bf16 conversion ----------------
__global__ __launch_bounds__(256) void cvt_w(
    const float* __restrict__ s0, const float* __restrict__ s1,
    const float* __restrict__ s2, const float* __restrict__ s3,
    const float* __restrict__ s4, const float* __restrict__ s5,
    short* __restrict__ dst)
{
  const float* srcs[6] = {s0, s1, s2, s3, s4, s5};
  int i = blockIdx.x * 256 + threadIdx.x;       // 6*65536 total
  dst[i] = f2b(srcs[i >> 16][i & 65535]);
}

// ---------------- LayerNorm: f32 in, bf16 out (kv path only) ----------------
__global__ __launch_bounds__(256) void ln_k(
    const float* __restrict__ x, const float* __restrict__ g,
    const float* __restrict__ bta, short* __restrict__ y)
{
  const int row = blockIdx.x, t = threadIdx.x;
  const size_t base = (size_t)row * 256;
  float v = x[base + t];
  float s1 = v, s2 = v * v;
  #pragma unroll
  for (int off = 32; off; off >>= 1){ s1 += __shfl_down(s1, off); s2 += __shfl_down(s2, off); }
  __shared__ float a1[4], a2[4];
  __shared__ float mu_s, rs_s;
  if ((t & 63) == 0){ a1[t >> 6] = s1; a2[t >> 6] = s2; }
  __syncthreads();
  if (t == 0){
    float S1 = a1[0] + a1[1] + a1[2] + a1[3];
    float S2 = a2[0] + a2[1] + a2[2] + a2[3];
    float mu = S1 * 0.00390625f;
    float var = S2 * 0.00390625f - mu * mu;
    mu_s = mu; rs_s = rsqrtf(var + 1e-5f);
  }
  __syncthreads();
  y[base + t] = f2b((v - mu_s) * rs_s * g[t] + bta[t]);
}

// ---------------- wide GEMM: C[M,256] = A[M,256] @ W[256,256]^T + b ----------------
// Block = 64 rows x 256 cols, 4 waves (wave: 16 rows, acc[16] f32x4).
// A staged ONCE to LDS; optionally LayerNorm'd in the prologue:
//   LNA=1: A is f32 (Af) + LN ; LNA=2: A is bf16 + LN.
// W double-buffered per 32-k-step (1 barrier/step).
// Epilogue: GELU / residual (RES=1 f32, RES=2 bf16) / f32 out / bf16 out /
//           kfrag (OT=1) / vfrag (OT=2).
template<int RES, int GELU, int OF, int OB, int OT, int LNA>
__global__ __launch_bounds__(256, 2) void gemmW(
    const short* __restrict__ A, const float* __restrict__ Af,
    const short* __restrict__ W,
    const float* __restrict__ bias,
    const float* __restrict__ resF, const short* __restrict__ resB,
    float* __restrict__ outF, short* __restrict__ outB,
    const float* __restrict__ lnag, const float* __restrict__ lnab)
{
  __shared__ short As[64][264];        // full A tile
  __shared__ short Ws[2][256][40];     // k-slice double buffer
  const int tid = threadIdx.x;
  const int m0 = blockIdx.x << 6;
  const int w = tid >> 6, lane = tid & 63;
  const int l15 = lane & 15, g = lane >> 4;

  // ---- stage A (once), optionally LayerNorm'd ----
  if (LNA){
    const int row = tid >> 2, c0 = (tid & 3) << 6;   // 4 threads/row, 64 cols each
    float vv[64];
    if (LNA == 1){
      const float* src = &Af[(size_t)(m0 + row) * 256 + c0];
      #pragma unroll
      for (int i = 0; i < 16; ++i) *(f32x4*)&vv[4 * i] = *(const f32x4*)&src[4 * i];
    } else {
      const short* src = &A[(size_t)(m0 + row) * 256 + c0];
      #pragma unroll
      for (int i = 0; i < 8; ++i){
        short8 s = *(const short8*)&src[8 * i];
        #pragma unroll
        for (int j = 0; j < 8; ++j) vv[8 * i + j] = b2f(s[j]);
      }
    }
    float s1 = 0.f, s2 = 0.f;
    #pragma unroll
    for (int i = 0; i < 64; ++i){ s1 += vv[i]; s2 += vv[i] * vv[i]; }
    s1 += __shfl_xor(s1, 1); s2 += __shfl_xor(s2, 1);
    s1 += __shfl_xor(s1, 2); s2 += __shfl_xor(s2, 2);
    const float mu = s1 * 0.00390625f;
    const float rs = rsqrtf(s2 * 0.00390625f - mu * mu + 1e-5f);
    #pragma unroll
    for (int i = 0; i < 8; ++i){
      f32x4 gv0 = *(const f32x4*)&lnag[c0 + 8 * i];
      f32x4 gv1 = *(const f32x4*)&lnag[c0 + 8 * i + 4];
      f32x4 bv0 = *(const f32x4*)&lnab[c0 + 8 * i];
      f32x4 bv1 = *(const f32x4*)&lnab[c0 + 8 * i + 4];
      short8 o;
      #pragma unroll
      for (int j = 0; j < 4; ++j) o[j] = f2b((vv[8 * i + j] - mu) * rs * gv0[j] + bv0[j]);
      #pragma unroll
      for (int j = 0; j < 4; ++j) o[4 + j] = f2b((vv[8 * i + 4 + j] - mu) * rs * gv1[j] + bv1[j]);
      *(short8*)&As[row][c0 + 8 * i] = o;
    }
  } else {
    #pragma unroll
    for (int it = 0; it < 8; ++it){
      int idx = tid + (it << 8);
      int row = idx >> 5, c = (idx & 31) << 3;
      *(short8*)&As[row][c] = *(const short8*)&A[(size_t)(m0 + row) * 256 + c];
    }
  }
  // ---- stage W k0=0 ----
  #pragma unroll
  for (int it = 0; it < 4; ++it){
    int row = (it << 6) + (tid >> 2), c = (tid & 3) << 3;
    *(short8*)&Ws[0][row][c] = *(const short8*)&W[(size_t)row * 256 + c];
  }
  __syncthreads();

  f32x4 acc[16];
  #pragma unroll
  for (int nt = 0; nt < 16; ++nt) acc[nt] = {0.f, 0.f, 0.f, 0.f};

  int cur = 0;
  for (int s = 0; s < 8; ++s){
    const int k0 = s << 5;
    short8 wreg[4];
    if (s < 7){
      #pragma unroll
      for (int it = 0; it < 4; ++it)
        wreg[it] = *(const short8*)&W[(size_t)((it << 6) + (tid >> 2)) * 256 + k0 + 32 + ((tid & 3) << 3)];
    }
    short8 af = *(const short8*)&As[(w << 4) + l15][k0 + (g << 3)];
    #pragma unroll
    for (int nt = 0; nt < 16; ++nt){
      short8 bf = *(const short8*)&Ws[cur][(nt << 4) + l15][g << 3];
      acc[nt] = __builtin_amdgcn_mfma_f32_16x16x32_bf16(af, bf, acc[nt], 0, 0, 0);
    }
    if (s < 7){
      #pragma unroll
      for (int it = 0; it < 4; ++it)
        *(short8*)&Ws[cur ^ 1][(it << 6) + (tid >> 2)][(tid & 3) << 3] = wreg[it];
    }
    __syncthreads();
    cur ^= 1;
  }

  const int row_l = (w << 4) + (g << 2);     // + r = wave's row within block
  #pragma unroll
  for (int nt = 0; nt < 16; ++nt){
    const int col = (nt << 4) + l15;
    const float bv = bias[col];
    #pragma unroll
    for (int r = 0; r < 4; ++r){
      const int m = m0 + row_l + r;
      const size_t idx = (size_t)m * 256 + col;
      float v = acc[nt][r] + bv;
      if (GELU) v = 0.5f * v * (1.0f + erff(v * 0.70710678118f));
      if (RES == 1) v += resF[idx];
      if (RES == 2) v += b2f(resB[idx]);
      if (OF) outF[idx] = v;
      if (OB) outB[idx] = f2b(v);
      if (OT == 1){   // kfrag: [b][h][nt][half][g][l15][8]
        const int b_ = m >> 8, kvr = m & 255;
        const int knt = kvr >> 4, kl = kvr & 15;
        const int h = col >> 6, half = (col >> 5) & 1, kg = (col >> 3) & 3, kj = col & 7;
        outB[(((((size_t)(b_ * 4 + h) * 16 + knt) * 2 + half) * 4 + kg) * 16 + kl) * 8 + kj] = f2b(v);
      }
      if (OT == 2){   // vfrag: [b][h][kk][n2][g][l15][8]
        const int b_ = m >> 8, kvj = m & 255;
        const int jp = (kvj & ~31) | (((kvj >> 2) & 3) << 3) | (((kvj >> 4) & 1) << 2) | (kvj & 3);
        const int h = col >> 6, dp = col & 63;
        const int kk = jp >> 5, vg = (jp >> 3) & 3, vj = jp & 7;
        const int vn2 = dp >> 4, vl = dp & 15;
        outB[(((((size_t)(b_ * 4 + h) * 8 + kk) * 4 + vn2) * 4 + vg) * 16 + vl) * 8 + vj] = f2b(v);
      }
    }
  }
}

// ---------------- fused MFMA attention: 1 block/CU, dbuf-LDS head phases ----------------
// Block: 512 thr = 8 waves x 16 q-rows = 128 q-rows; grid 32x8 = 256 blocks (1/CU).
// Per head phase: K+V frags (64KB, linear layout) async-staged to LDS
// (global_load_lds w16), double-buffered so staging h+1 overlaps compute h.
// 1 barrier/phase. Swapped QK^T: lane(l15,g) holds P[q=l15][kv=16nt+4g+r];
// softmax fully in-lane (cw packed in regs); PV via kv-permuted V frags;
// am accumulated in-wave across head phases.
__global__ __launch_bounds__(512, 2) void attn_k(
    const short* __restrict__ Qb, const short* __restrict__ Kf,
    const short* __restrict__ Vf, const float* __restrict__ cw,
    short* __restrict__ ctx, float* __restrict__ am_out)
{
  extern __shared__ __align__(16) short smem[];   // [2][32768]: per buf K 16384 + V 16384 shorts
  const int b = blockIdx.y;
  const int q0 = blockIdx.x << 7;
  const int tid = threadIdx.x;
  const int w = tid >> 6, lane = tid & 63;
  const int l15 = lane & 15, g = lane >> 4;
  const size_t qw = (size_t)b * 4096 + q0 + (w << 4);   // wave's first q row

  // stage K+V frags of head h_ into LDS buffer buf_ (4096 chunks of 16B, 512 thr x 8)
#define STAGE(buf_, h_) do{                                                          \
    const short* ks_ = Kf + (((size_t)(b * 4 + (h_))) << 14);                        \
    const short* vs_ = Vf + (((size_t)(b * 4 + (h_))) << 14);                        \
    short* kd_ = smem + (buf_) * 32768;                                              \
    short* vd_ = kd_ + 16384;                                                        \
    _Pragma("unroll")                                                                \
    for (int it_ = 0; it_ < 4; ++it_){                                               \
      int c_ = (it_ << 9) + tid;                                                     \
      __builtin_amdgcn_global_load_lds((const AS1 void*)(ks_ + (c_ << 3)),           \
                                       (AS3 void*)(kd_ + (c_ << 3)), 16, 0, 0);      \
      __builtin_amdgcn_global_load_lds((const AS1 void*)(vs_ + (c_ << 3)),           \
                                       (AS3 void*)(vd_ + (c_ << 3)), 16, 0, 0);      \
    }                                                                                \
  }while(0)

  STAGE(0, 0);

  // clustering weights (bf16-packed) + attn_matrix accumulator, in registers.
  // element (nt, r) <-> cw[(qw + l15)*256 + 16*nt + 4*g + r]
  unsigned cwp[16][2];
  f32x4 am[16];
  #pragma unroll
  for (int nt = 0; nt < 16; ++nt){
    f32x4 c = *(const f32x4*)&cw[(qw + l15) * 256 + (nt << 4) + (g << 2)];
    cwp[nt][0] = pk2(c[0], c[1]);
    cwp[nt][1] = pk2(c[2], c[3]);
    am[nt] = {0.f, 0.f, 0.f, 0.f};
  }
  __syncthreads();                       // head-0 staging complete

  for (int h = 0; h < 4; ++h){
    if (h < 3) STAGE((h + 1) & 1, h + 1);          // prefetch next head into other buf
    const short* kls = smem + (h & 1) * 32768;
    const short* vls = kls + 16384;
    short8 qf0 = *(const short8*)&Qb[(qw + l15) * 256 + (h << 6) + (g << 3)];
    short8 qf1 = *(const short8*)&Qb[(qw + l15) * 256 + (h << 6) + 32 + (g << 3)];

    // ---- scores: swapped operands, conflict-free lane-contiguous ds_read_b128 ----
    f32x4 acc[16];
    #pragma unroll
    for (int nt = 0; nt < 16; ++nt) acc[nt] = {0.f, 0.f, 0.f, 0.f};
    #pragma unroll
    for (int nt = 0; nt < 16; ++nt){
      short8 kf0 = *(const short8*)&kls[(nt << 10) + (lane << 3)];
      acc[nt] = __builtin_amdgcn_mfma_f32_16x16x32_bf16(kf0, qf0, acc[nt], 0, 0, 0);
      short8 kf1 = *(const short8*)&kls[(nt << 10) + 512 + (lane << 3)];
      acc[nt] = __builtin_amdgcn_mfma_f32_16x16x32_bf16(kf1, qf1, acc[nt], 0, 0, 0);
    }
    // ---- softmax, fully in-lane (row q = l15; partners at lane^16, lane^32) ----
    float mx = -3.4e38f;
    #pragma unroll
    for (int nt = 0; nt < 16; ++nt){
      float c0 = __uint_as_float(cwp[nt][0] << 16);
      float c1 = __uint_as_float(cwp[nt][0] & 0xffff0000u);
      float c2 = __uint_as_float(cwp[nt][1] << 16);
      float c3 = __uint_as_float(cwp[nt][1] & 0xffff0000u);
      acc[nt][0] = acc[nt][0] * 0.125f + c0;
      acc[nt][1] = acc[nt][1] * 0.125f + c1;
      acc[nt][2] = acc[nt][2] * 0.125f + c2;
      acc[nt][3] = acc[nt][3] * 0.125f + c3;
      mx = fmaxf(mx, fmaxf(fmaxf(acc[nt][0], acc[nt][1]), fmaxf(acc[nt][2], acc[nt][3])));
    }
    mx = fmaxf(mx, __shfl_xor(mx, 16));
    mx = fmaxf(mx, __shfl_xor(mx, 32));
    float sm = 0.f;
    #pragma unroll
    for (int nt = 0; nt < 16; ++nt){
      #pragma unroll
      for (int r = 0; r < 4; ++r){
        float e = __expf(acc[nt][r] - mx);
        acc[nt][r] = e; sm += e;
      }
    }
    sm += __shfl_xor(sm, 16);
    sm += __shfl_xor(sm, 32);
    float inv = 1.f / sm;
    #pragma unroll
    for (int nt = 0; nt < 16; ++nt){
      #pragma unroll
      for (int r = 0; r < 4; ++r){
        float p = acc[nt][r] * inv;
        acc[nt][r] = p;
        am[nt][r] += 0.25f * p;
      }
    }
    // ---- ctx = P @ V : in-lane A packs; conflict-free V-frag ds_reads ----
    f32x4 oc[4] = {{0,0,0,0},{0,0,0,0},{0,0,0,0},{0,0,0,0}};
    #pragma unroll
    for (int kk = 0; kk < 8; ++kk){
      union { short8 s; unsigned u[4]; } pa;
      pa.u[0] = pk2(acc[2 * kk][0],     acc[2 * kk][1]);
      pa.u[1] = pk2(acc[2 * kk][2],     acc[2 * kk][3]);
      pa.u[2] = pk2(acc[2 * kk + 1][0], acc[2 * kk + 1][1]);
      pa.u[3] = pk2(acc[2 * kk + 1][2], acc[2 * kk + 1][3]);
      #pragma unroll
      for (int n2 = 0; n2 < 4; ++n2){
        short8 vb = *(const short8*)&vls[(((kk << 2) + n2) << 9) + (lane << 3)];
        oc[n2] = __builtin_amdgcn_mfma_f32_16x16x32_bf16(pa.s, vb, oc[n2], 0, 0, 0);
      }
    }
    // lane holds ctx[q = 4g + r][d = 16*n2 + l15]
    #pragma unroll
    for (int n2 = 0; n2 < 4; ++n2)
      #pragma unroll
      for (int r = 0; r < 4; ++r)
        ctx[(qw + (g << 2) + r) * 256 + (h << 6) + (n2 << 4) + l15] = f2b(oc[n2][r]);

    __syncthreads();   // drains stage loads (vmcnt0 before barrier) + all waves done with kls/vls
  }
  #pragma unroll
  for (int nt = 0; nt < 16; ++nt)
    *(f32x4*)&am_out[(qw + l15) * 256 + (nt << 4) + (g << 2)] = am[nt];
#undef STAGE
}

extern "C" void kernel_launch(void* const* d_in, const int* in_sizes, int n_in,
                              void* d_out, int out_size, void* d_ws, size_t ws_size,
                              hipStream_t stream)
{
  const float* node_emb = (const float*)d_in[0];
  const float* cluster  = (const float*)d_in[1];
  const float* cw       = (const float*)d_in[2];
  const float* ln_q_g   = (const float*)d_in[3];
  const float* ln_q_b   = (const float*)d_in[4];
  const float* ln_kv_g  = (const float*)d_in[5];
  const float* ln_kv_b  = (const float*)d_in[6];
  const float* ln_o_g   = (const float*)d_in[7];
  const float* ln_o_b   = (const float*)d_in[8];
  const float* W_q  = (const float*)d_in[9];  const float* b_q  = (const float*)d_in[10];
  const float* W_k  = (const float*)d_in[11]; const float* b_k  = (const float*)d_in[12];
  const float* W_v  = (const float*)d_in[13]; const float* b_v  = (const float*)d_in[14];
  const float* W_o  = (const float*)d_in[15]; const float* b_o  = (const float*)d_in[16];
  const float* W_m1 = (const float*)d_in[17]; const float* b_m1 = (const float*)d_in[18];
  const float* W_m2 = (const float*)d_in[19]; const float* b_m2 = (const float*)d_in[20];

  char* ws = (char*)d_ws;
  short* Wbf   = (short*)ws;                                   // 786,432 B (6 x 64K bf16)
  short* n1    = (short*)(ws + 786432);                        // 16.78 MB: ctx -> h1
  short* n2    = (short*)(ws + 786432 + 16777216);             // 16.78 MB: Q -> x (bf16)
  short* kvin  = (short*)(ws + 786432 + 2 * 16777216);         // 1 MB
  short* kfrag = (short*)(ws + 786432 + 2 * 16777216 + 1048576);
  short* vfrag = (short*)(ws + 786432 + 2 * 16777216 + 2 * 1048576);

  float* outF = (float*)d_out;            // first half: final out (written only by M2)
  float* amof = (float*)d_out + 8388608;  // second half: attn_matrix

  // allow 128 KB dynamic LDS for attn_k (idempotent; not a stream op)
  hipFuncSetAttribute((const void*)attn_k, hipFuncAttributeMaxDynamicSharedMemorySize, 131072);

  cvt_w<<<1536, 256, 0, stream>>>(W_q, W_k, W_v, W_o, W_m1, W_m2, Wbf);
  ln_k<<<2048, 256, 0, stream>>>(cluster, ln_kv_g, ln_kv_b, kvin);
  // Q projection with fused input-LayerNorm (reads node_emb f32 directly)
  gemmW<0,0,0,1,0,1><<<512, 256, 0, stream>>>(nullptr, node_emb, Wbf, b_q,
      nullptr, nullptr, nullptr, n2, ln_q_g, ln_q_b);
  // K / V projections -> fragment-order buffers
  gemmW<0,0,0,0,1,0><<<32, 256, 0, stream>>>(kvin, nullptr, Wbf + 65536, b_k,
      nullptr, nullptr, nullptr, kfrag, nullptr, nullptr);
  gemmW<0,0,0,0,2,0><<<32, 256, 0, stream>>>(kvin, nullptr, Wbf + 131072, b_v,
      nullptr, nullptr, nullptr, vfrag, nullptr, nullptr);
  // attention (ctx -> n1, attn_matrix -> d_out 2nd half)
  attn_k<<<dim3(32, 8), 512, 131072, stream>>>(n2, kfrag, vfrag, cw, n1, amof);
  // O proj + residual(node_emb f32) -> x as bf16 into n2 (Q dead)
  gemmW<1,0,0,1,0,0><<<512, 256, 0, stream>>>(n1, nullptr, Wbf + 196608, b_o,
      node_emb, nullptr, nullptr, n2, nullptr, nullptr);
  // MLP1 with fused LN(x) prologue + GELU -> n1
  gemmW<0,1,0,1,0,2><<<512, 256, 0, stream>>>(n2, nullptr, Wbf + 262144, b_m1,
      nullptr, nullptr, nullptr, n1, ln_o_g, ln_o_b);
  // MLP2 + residual(x bf16) -> final out f32
  gemmW<2,0,1,0,0,0><<<512, 256, 0, stream>>>(n1, nullptr, Wbf + 327680, b_m2,
      nullptr, n2, outF, nullptr, nullptr, nullptr);
}